// Round 9
// baseline (65.933 us; speedup 1.0000x reference)
//
#include <hip/hip_runtime.h>
#include <math.h>

#define NROWS 4096
#define D 128
#define SPC 8
#define KRET 7
#define MARGIN 0.2f
#define NTILE 32              // 4096/128 column tiles
#define CPT 14                // candidates per (row, tile): 2 quadrants x top-7
#define CPR (NTILE * CPT)     // 448 candidates per row
#define NBLK (NROWS / 4)      // merge grid

typedef unsigned long long u64;
typedef unsigned int u32;
typedef __attribute__((ext_vector_type(8))) short short8;   // 8 bf16 (4 VGPRs)
typedef __attribute__((ext_vector_type(4))) float f32x4;    // MFMA accumulator

__device__ __forceinline__ u32 minu32(u32 a, u32 b) { return a < b ? a : b; }
__device__ __forceinline__ u32 maxu32(u32 a, u32 b) { return a > b ? a : b; }

// bf16 round-to-nearest-even
__device__ __forceinline__ ushort f2bf_rne(float x) {
    unsigned u = __float_as_uint(x);
    unsigned r = (u + 0x7fffu + ((u >> 16) & 1u)) >> 16;
    return (ushort)r;
}

// ws layout (floats):
//   [0..1]               (fallback accums)   [2] merge completion counter (u32)
//   [4096 .. 8191]       diag
//   [8192 .. 40959]      posd (4096 x 8 f32, clamped d^2)
//   [40960 .. 106495]    embH  (4096x128 bf16)
//   [106496 .. 172031]   emb1H (4096x128 bf16)
//   [172032 .. 2007039]  cand (u32, 4096 x 448)
//   [2007040 ..]         rowls (4096), rowcnt (4096)

// ---- prep: bf16 round of both matrices + exact f32 Gram diagonal + counter reset ----
__global__ __launch_bounds__(256) void prep_kernel(const float* __restrict__ emb,
                                                   const float* __restrict__ emb1,
                                                   ushort* __restrict__ embH,
                                                   ushort* __restrict__ emb1H,
                                                   float* __restrict__ diag,
                                                   u32* __restrict__ ctr) {
    if (blockIdx.x == 0 && threadIdx.x == 0) ctr[0] = 0u;   // reset last-block counter
    const int lane = threadIdx.x & 63;
    const int row = blockIdx.x * 4 + (threadIdx.x >> 6);
    const size_t base = (size_t)row * D + 2 * lane;
    const float2 a = *(const float2*)(emb + base);
    const float2 b = *(const float2*)(emb1 + base);

    *(ushort2*)(embH + base)  = make_ushort2(f2bf_rne(a.x), f2bf_rne(a.y));
    *(ushort2*)(emb1H + base) = make_ushort2(f2bf_rne(b.x), f2bf_rne(b.y));

    float s = a.x * b.x + a.y * b.y;
#pragma unroll
    for (int off = 1; off < 64; off <<= 1) s += __shfl_xor(s, off, 64);
    if (lane == 0) diag[row] = s;
}

// ---- dist tile via bf16 MFMA (LDS-staged) + fused per-quadrant top-7 ----
// 128x128 tile, 4 waves; K staged in 2 phases of 64 through LDS [128][72] bf16.
// After k-loop the staging LDS is overlaid by 4 per-wave quadrant score bufs
// [64][72] u16 (stride 144B: 16B-aligned rows for ds_read_b128; write cols
// XOR-swizzled by (lg<<3) -> 2-way banks on writes, b128-clean reads).
__global__ __launch_bounds__(256, 4) void dist_mfma(const ushort* __restrict__ embH,
                                                    const ushort* __restrict__ emb1H,
                                                    const int* __restrict__ labels,
                                                    const int* __restrict__ labels1,
                                                    const float* __restrict__ diag,
                                                    float* __restrict__ posd, u32* __restrict__ cand) {
    __shared__ ushort smem[2][9216];      // AH, BH: [128][72] bf16 each = 36864 B
    __shared__ float sdA[128], sdB[128];
    __shared__ int sLi[128], sLj[128];
    ushort* AH = smem[0];
    ushort* BH = smem[1];

    const int t = threadIdx.x;
    const int i0 = blockIdx.y * 128, j0 = blockIdx.x * 128;
    const int w = t >> 6, l = t & 63;

    if (t < 128) { sdA[t] = diag[i0 + t]; sLi[t] = labels1[i0 + t]; }
    else         { sdB[t - 128] = diag[j0 + t - 128]; sLj[t - 128] = labels[j0 + t - 128]; }

    const int R = (w >> 1) * 64, C = (w & 1) * 64;
    const int lr = l & 15, lg = l >> 4;

    f32x4 acc[4][4];
#pragma unroll
    for (int m = 0; m < 4; ++m)
#pragma unroll
        for (int n = 0; n < 4; ++n) acc[m][n] = (f32x4){0.f, 0.f, 0.f, 0.f};

    bool hasPos = false;
    const int srow = t & 127;
    for (int p = 0; p < 2; ++p) {
        if (p) __syncthreads();            // phase-0 frag reads complete before restage
#pragma unroll
        for (int n = 0; n < 4; ++n) {
            const int c = n * 2 + (t >> 7);                         // 0..7
            const size_t gA = (size_t)(i0 + srow) * D + p * 64 + c * 8;
            const size_t gB = (size_t)(j0 + srow) * D + p * 64 + c * 8;
            const int ld = srow * 72 + c * 8;
            *(uint4*)(AH + ld) = *(const uint4*)(embH + gA);
            *(uint4*)(BH + ld) = *(const uint4*)(emb1H + gB);
        }
        __syncthreads();

        if (p == 0) {   // per-quadrant positive gate: label-range intersection
            int mnA = sLi[R + l], mxA = mnA;
            int mnB = sLj[C + l], mxB = mnB;
#pragma unroll
            for (int off = 1; off < 64; off <<= 1) {
                mnA = min(mnA, __shfl_xor(mnA, off, 64));
                mxA = max(mxA, __shfl_xor(mxA, off, 64));
                mnB = min(mnB, __shfl_xor(mnB, off, 64));
                mxB = max(mxB, __shfl_xor(mxB, off, 64));
            }
            hasPos = !(mxA < mnB || mxB < mnA);
        }

#pragma unroll
        for (int ks = 0; ks < 2; ++ks) {
            const int koff = ks * 32 + lg * 8;
            short8 ah[4], bh[4];
#pragma unroll
            for (int m = 0; m < 4; ++m) {
                ah[m] = *(const short8*)(AH + (R + 16 * m + lr) * 72 + koff);
                bh[m] = *(const short8*)(BH + (C + 16 * m + lr) * 72 + koff);
            }
#pragma unroll
            for (int m = 0; m < 4; ++m)
#pragma unroll
                for (int n = 0; n < 4; ++n)
                    acc[m][n] = __builtin_amdgcn_mfma_f32_16x16x32_bf16(ah[m], bh[n], acc[m][n], 0, 0, 0);
        }
    }

    // preload diag (and labels if needed) to regs; sdA/sdB/sLi/sLj are NOT overlaid
    float sdA_r[16], sdB_c[4];
    int sLi_r[16], sLj_c[4];
#pragma unroll
    for (int m = 0; m < 4; ++m)
#pragma unroll
        for (int r = 0; r < 4; ++r) sdA_r[m * 4 + r] = sdA[R + 16 * m + 4 * lg + r];
#pragma unroll
    for (int n = 0; n < 4; ++n) sdB_c[n] = sdB[C + 16 * n + lr];
    if (hasPos) {
#pragma unroll
        for (int m = 0; m < 4; ++m)
#pragma unroll
            for (int r = 0; r < 4; ++r) sLi_r[m * 4 + r] = sLi[R + 16 * m + 4 * lg + r];
#pragma unroll
        for (int n = 0; n < 4; ++n) sLj_c[n] = sLj[C + 16 * n + lr];
    }

    __syncthreads();   // all waves' frag reads done; staging area becomes score bufs

    // epilogue: clamped d^2 -> bf16 u16 scores into this wave's quadrant buffer.
    // C/D layout (m89-verified): col = lane&15, row = (lane>>4)*4 + reg
    ushort* dq = ((ushort*)(void*)smem) + w * (64 * 72);
    const int cxor = lg << 3;          // write swizzle key == reader's (row>>2)&3 << 3
    if (!hasPos) {
#pragma unroll
        for (int m = 0; m < 4; ++m)
#pragma unroll
            for (int n = 0; n < 4; ++n)
#pragma unroll
                for (int r = 0; r < 4; ++r) {
                    const int row = 16 * m + 4 * lg + r;
                    const int col = 16 * n + lr;
                    const float d2c = fmaxf(sdA_r[m * 4 + r] + sdB_c[n] - 2.f * acc[m][n][r], 1e-4f);
                    dq[row * 72 + (col ^ cxor)] = f2bf_rne(d2c);
                }
    } else {
#pragma unroll
        for (int m = 0; m < 4; ++m)
#pragma unroll
            for (int n = 0; n < 4; ++n)
#pragma unroll
                for (int r = 0; r < 4; ++r) {
                    const int row = 16 * m + 4 * lg + r;
                    const int col = 16 * n + lr;
                    const int gi = i0 + R + row, gj = j0 + C + col;
                    const float d2c = fmaxf(sdA_r[m * 4 + r] + sdB_c[n] - 2.f * acc[m][n][r], 1e-4f);
                    const bool pos = (sLj_c[n] == sLi_r[m * 4 + r]) && (gi != gj);
                    if (pos) posd[(size_t)gi * SPC + (gj & (SPC - 1))] = d2c;
                    dq[row * 72 + (col ^ cxor)] = pos ? (ushort)0xFFFFu : f2bf_rne(d2c);
                }
    }

    // wave-local sync: this wave wrote exactly the quadrant it scans (rule 18 fence)
    asm volatile("s_waitcnt lgkmcnt(0)" ::: "memory");
    __builtin_amdgcn_sched_barrier(0);

    // selection: 1 thread per row; 8x ds_read_b128 + dual-insert sorted-7.
    // u32 pack (score16|col12): exact (score, col) lex order = reference tie-break.
    {
        u32 s[KRET];
#pragma unroll
        for (int k = 0; k < KRET; ++k) s[k] = 0xFFFFFFFFu;
        const ushort* dr = dq + l * 72;            // byte addr l*144: 16B-aligned
        const int xorv = (l >> 2) & 3;             // un-swizzle key for this row
        const u32 cbase = (u32)(j0 + C);
#pragma unroll
        for (int k = 0; k < 8; ++k) {
            const uint4 v4 = *(const uint4*)(dr + 8 * k);
            const u32 cb = cbase + 8u * (u32)(k ^ xorv);
            const u32 wd[4] = {v4.x, v4.y, v4.z, v4.w};
#pragma unroll
            for (int i = 0; i < 4; ++i) {
                const u32 c0 = cb + 2 * i;
                const u32 p0 = (wd[i] << 16) | c0;
                const u32 p1 = (wd[i] & 0xFFFF0000u) | (c0 + 1);
                const u32 q0 = minu32(p0, p1);
                const u32 q1 = maxu32(p0, p1);
                s[6] = minu32(s[6], minu32(maxu32(s[5], q0), maxu32(s[4], q1)));
                s[5] = minu32(s[5], minu32(maxu32(s[4], q0), maxu32(s[3], q1)));
                s[4] = minu32(s[4], minu32(maxu32(s[3], q0), maxu32(s[2], q1)));
                s[3] = minu32(s[3], minu32(maxu32(s[2], q0), maxu32(s[1], q1)));
                s[2] = minu32(s[2], minu32(maxu32(s[1], q0), maxu32(s[0], q1)));
                s[1] = minu32(s[1], minu32(maxu32(s[0], q0), q1));
                s[0] = minu32(s[0], q0);
            }
        }
        u32* cw = cand + (size_t)(i0 + R + l) * CPR + (j0 >> 7) * CPT + (C >> 6) * KRET;
#pragma unroll
        for (int k = 0; k < KRET; ++k) cw[k] = s[k];
    }
}

// ---- merge 448 u32 candidates/row -> top-7, validity, loss; last block finalizes ----
__global__ __launch_bounds__(256) void merge_kernel(const float* __restrict__ emb,
                                                    const float* __restrict__ posd,
                                                    const u32* __restrict__ cand,
                                                    float* __restrict__ rowls,
                                                    float* __restrict__ rowcnt,
                                                    u32* __restrict__ ctr,
                                                    float* __restrict__ out) {
    __shared__ float s_ls[4], s_cnt[4];
    __shared__ int s_last;
    const int lane = threadIdx.x & 63;
    const int wv = threadIdx.x >> 6;
    const int i = blockIdx.x * 4 + wv;
    const u32* cr = cand + (size_t)i * CPR;
    u32 e[7];
#pragma unroll
    for (int q = 0; q < 7; ++q) e[q] = cr[q * 64 + lane];

    u32 w[KRET];
#pragma unroll
    for (int r = 0; r < KRET; ++r) {
        u32 m = e[0];
#pragma unroll
        for (int q = 1; q < 7; ++q) m = minu32(m, e[q]);
#pragma unroll
        for (int off = 1; off < 64; off <<= 1) m = minu32(m, (u32)__shfl_xor((int)m, off, 64));
        w[r] = m;
#pragma unroll
        for (int q = 0; q < 7; ++q) e[q] = (e[q] == m) ? 0xFFFFFFFFu : e[q];
    }

    // sort winners by column index: rotate to (col12 << 20 | score16 << 4), Batcher-8
    u32 s[8];
#pragma unroll
    for (int r = 0; r < KRET; ++r) s[r] = (w[r] << 20) | (w[r] >> 12);
    s[7] = 0xFFFFFFFFu;
#define CE(x, y) { u32 lo = minu32(s[x], s[y]); u32 hi = maxu32(s[x], s[y]); s[x] = lo; s[y] = hi; }
    CE(0,1) CE(2,3) CE(4,5) CE(6,7)
    CE(0,2) CE(1,3) CE(4,6) CE(5,7)
    CE(1,2) CE(5,6)
    CE(0,4) CE(1,5) CE(2,6) CE(3,7)
    CE(2,4) CE(3,5)
    CE(1,2) CE(3,4) CE(5,6)
#undef CE

    const int ig = i & (SPC - 1);
    float ls = 0.f, cnt = 0.f;
    bool any = false;
    bool v[KRET];
    int nidx[KRET];
#pragma unroll
    for (int k = 0; k < KRET; ++k) {
        nidx[k] = (int)(s[k] >> 20);
        const float d2n = __uint_as_float(((s[k] >> 4) & 0xFFFF0u) << 12);  // score16 << 16
        const float dneg = sqrtf(d2n);
        const int m = k + (k >= ig ? 1 : 0);
        const float dp = sqrtf(posd[(size_t)i * SPC + m]);
        v[k] = dp < dneg + MARGIN;       // wave-uniform
        any = any || v[k];
    }

    if (any) {
        const float a0 = emb[(size_t)i * D + lane];
        const float a1 = emb[(size_t)i * D + 64 + lane];
#pragma unroll
        for (int k = 0; k < KRET; ++k) {
            if (v[k]) {
                const int m = k + (k >= ig ? 1 : 0);
                const int tp = (i & ~(SPC - 1)) + m;
                const int tn = nidx[k];
                float d0 = emb[(size_t)tp * D + lane] - a0;
                float d1 = emb[(size_t)tp * D + 64 + lane] - a1;
                float sp = d0 * d0 + d1 * d1;
                float g0 = emb[(size_t)tn * D + lane] - a0;
                float g1 = emb[(size_t)tn * D + 64 + lane] - a1;
                float sn = g0 * g0 + g1 * g1;
#pragma unroll
                for (int off = 1; off < 64; off <<= 1) {
                    sp += __shfl_xor(sp, off, 64);
                    sn += __shfl_xor(sn, off, 64);
                }
                ls += (sqrtf(sp + 1e-8f) + MARGIN) + fmaxf(MARGIN - sqrtf(sn + 1e-8f), 0.f);
                cnt += 1.f;
            }
        }
    }
    if (lane == 0) { s_ls[wv] = ls; s_cnt[wv] = cnt; }
    __syncthreads();

    // single-writer publish (canonical last-block pattern): thread 0 stores all
    // 4 rows' partials, fences, bumps the counter.
    if (threadIdx.x == 0) {
#pragma unroll
        for (int q = 0; q < 4; ++q) {
            rowls[blockIdx.x * 4 + q]  = s_ls[q];
            rowcnt[blockIdx.x * 4 + q] = s_cnt[q];
        }
        __threadfence();
        const u32 old = atomicAdd(ctr, 1u);
        s_last = (old == (u32)(NBLK - 1));
    }
    __syncthreads();

    if (s_last) {     // exactly one block: deterministic fixed-order reduction
        __threadfence();
        const int t = threadIdx.x;
        float L = 0.f, Cn = 0.f;
#pragma unroll
        for (int q = 0; q < NROWS / 256; ++q) {
            L  += rowls[q * 256 + t];
            Cn += rowcnt[q * 256 + t];
        }
#pragma unroll
        for (int off = 1; off < 64; off <<= 1) {
            L  += __shfl_xor(L, off, 64);
            Cn += __shfl_xor(Cn, off, 64);
        }
        if ((t & 63) == 0) { s_ls[t >> 6] = L; s_cnt[t >> 6] = Cn; }
        __syncthreads();
        if (t == 0) {
            const float Lt = s_ls[0] + s_ls[1] + s_ls[2] + s_ls[3];
            const float Ct = s_cnt[0] + s_cnt[1] + s_cnt[2] + s_cnt[3];
            out[0] = Ct > 0.f ? Lt / Ct : Lt;
        }
    }
}

// ---------------- Fallback path (round-1, only if ws too small) ----------------
__global__ __launch_bounds__(256) void diag_kernel(const float* __restrict__ emb,
                                                   const float* __restrict__ emb1,
                                                   float* __restrict__ diag) {
    int wave = threadIdx.x >> 6;
    int lane = threadIdx.x & 63;
    int row = blockIdx.x * 4 + wave;
    const float* a = emb + (size_t)row * D;
    const float* b = emb1 + (size_t)row * D;
    float s = a[lane] * b[lane] + a[lane + 64] * b[lane + 64];
    for (int off = 32; off > 0; off >>= 1) s += __shfl_down(s, off, 64);
    if (lane == 0) diag[row] = s;
}

__global__ __launch_bounds__(256) void main_kernel(const float* __restrict__ emb,
                                                   const float* __restrict__ emb1,
                                                   const int* __restrict__ labels,
                                                   const int* __restrict__ labels1,
                                                   const float* __restrict__ diag,
                                                   float* __restrict__ ws_acc) {
    const int i = blockIdx.x;
    const int tid = threadIdx.x;
    __shared__ float s_anchor[D];
    __shared__ float s_posd[SPC];
    __shared__ u64 s_red[4];
    __shared__ u64 s_win;
    __shared__ int s_negidx[KRET];
    __shared__ float s_negd[KRET];
    __shared__ float s_dreal[2 * KRET];

    if (tid < D) s_anchor[tid] = emb[(size_t)i * D + tid];
    __syncthreads();
    const float diag_i = diag[i];
    const int li = labels1[i];
    float score[16];
#pragma unroll
    for (int it = 0; it < 16; ++it) {
        int j = it * 256 + tid;
        const float4* r = (const float4*)(emb1 + (size_t)j * D);
        float acc = 0.f;
#pragma unroll
        for (int q = 0; q < D / 4; ++q) {
            float4 vv = r[q];
            acc = fmaf(vv.x, s_anchor[4 * q + 0], acc);
            acc = fmaf(vv.y, s_anchor[4 * q + 1], acc);
            acc = fmaf(vv.z, s_anchor[4 * q + 2], acc);
            acc = fmaf(vv.w, s_anchor[4 * q + 3], acc);
        }
        float d2 = diag_i + diag[j] - 2.f * acc;
        float dist = sqrtf(fmaxf(d2, 1e-4f));
        bool is_pos = (labels[j] == li) && (j != i);
        if (is_pos) s_posd[j & (SPC - 1)] = dist;
        score[it] = dist + (is_pos ? 1e6f : 0.f);
    }
    __syncthreads();
    for (int r = 0; r < KRET; ++r) {
        u64 best = ~0ull;
#pragma unroll
        for (int it = 0; it < 16; ++it) {
            u64 p = ((u64)__float_as_uint(score[it]) << 32) | (unsigned)(it * 256 + tid);
            best = best < p ? best : p;
        }
        for (int off = 32; off > 0; off >>= 1) {
            u64 o = __shfl_down(best, off, 64);
            best = best < o ? best : o;
        }
        if ((tid & 63) == 0) s_red[tid >> 6] = best;
        __syncthreads();
        if (tid == 0) {
            u64 w2 = s_red[0];
            w2 = w2 < s_red[1] ? w2 : s_red[1];
            w2 = w2 < s_red[2] ? w2 : s_red[2];
            w2 = w2 < s_red[3] ? w2 : s_red[3];
            s_win = w2;
        }
        __syncthreads();
        u64 w2 = s_win;
        int cj = (int)(w2 & 0xffffffffu);
        if (tid == (cj & 255)) score[cj >> 8] = 1e30f;
        if (tid == 0) { s_negidx[r] = cj; s_negd[r] = __uint_as_float((unsigned)(w2 >> 32)); }
        __syncthreads();
    }
    if (tid == 0) {
        for (int a = 1; a < KRET; ++a) {
            int ix = s_negidx[a]; float dv = s_negd[a];
            int b = a - 1;
            while (b >= 0 && s_negidx[b] > ix) {
                s_negidx[b + 1] = s_negidx[b]; s_negd[b + 1] = s_negd[b]; --b;
            }
            s_negidx[b + 1] = ix; s_negd[b + 1] = dv;
        }
    }
    __syncthreads();
    {
        int wave = tid >> 6, lane = tid & 63;
        int gb = i & ~(SPC - 1);
        for (int p = wave; p < 2 * KRET; p += 4) {
            int tgt;
            if (p < KRET) {
                int k = p;
                int m = k + (k >= (i & (SPC - 1)) ? 1 : 0);
                tgt = gb + m;
            } else tgt = s_negidx[p - KRET];
            float d0 = emb[(size_t)tgt * D + lane] - s_anchor[lane];
            float d1 = emb[(size_t)tgt * D + 64 + lane] - s_anchor[64 + lane];
            float s = d0 * d0 + d1 * d1;
            for (int off = 32; off > 0; off >>= 1) s += __shfl_down(s, off, 64);
            if (lane == 0) s_dreal[p] = sqrtf(s + 1e-8f);
        }
    }
    __syncthreads();
    if (tid == 0) {
        float ls = 0.f, cnt = 0.f;
        for (int k = 0; k < KRET; ++k) {
            int m = k + (k >= (i & (SPC - 1)) ? 1 : 0);
            if (s_posd[m] < s_negd[k] + MARGIN) {
                ls += (s_dreal[k] + MARGIN) + fmaxf(MARGIN - s_dreal[KRET + k], 0.f);
                cnt += 1.f;
            }
        }
        if (ls != 0.f) atomicAdd(&ws_acc[0], ls);
        if (cnt != 0.f) atomicAdd(&ws_acc[1], cnt);
    }
}

__global__ void finalize_ws(const float* __restrict__ ws_acc, float* __restrict__ out) {
    float ls = ws_acc[0], cnt = ws_acc[1];
    out[0] = cnt > 0.f ? ls / cnt : ls;
}

extern "C" void kernel_launch(void* const* d_in, const int* in_sizes, int n_in,
                              void* d_out, int out_size, void* d_ws, size_t ws_size,
                              hipStream_t stream) {
    const float* emb     = (const float*)d_in[0];
    const int*   labels  = (const int*)d_in[1];
    const float* emb1    = (const float*)d_in[2];
    const int*   labels1 = (const int*)d_in[3];
    float* ws = (float*)d_ws;

    const size_t need = (size_t)2015232 * sizeof(float);
    if (ws_size >= need) {
        u32*    ctr    = (u32*)(ws + 2);
        float*  diag   = ws + 4096;
        float*  posd   = ws + 8192;
        ushort* embH   = (ushort*)(ws + 40960);
        ushort* emb1H  = (ushort*)(ws + 106496);
        u32*    cand   = (u32*)(ws + 172032);
        float*  rowls  = ws + 2007040;
        float*  rowcnt = ws + 2011136;

        prep_kernel<<<NROWS / 4, 256, 0, stream>>>(emb, emb1, embH, emb1H, diag, ctr);
        dim3 grid(NROWS / 128, NROWS / 128);
        dist_mfma<<<grid, 256, 0, stream>>>(embH, emb1H, labels, labels1, diag, posd, cand);
        merge_kernel<<<NBLK, 256, 0, stream>>>(emb, posd, cand, rowls, rowcnt, ctr, (float*)d_out);
    } else {
        hipMemsetAsync(d_ws, 0, 2 * sizeof(float), stream);
        float* diag = ws + 2;
        diag_kernel<<<NROWS / 4, 256, 0, stream>>>(emb, emb1, diag);
        main_kernel<<<NROWS, 256, 0, stream>>>(emb, emb1, labels, labels1, diag, ws);
        finalize_ws<<<1, 1, 0, stream>>>(ws, (float*)d_out);
    }
}

// Round 10
// 52.092 us; speedup vs baseline: 1.2657x; 1.2657x over previous
//
#include <hip/hip_runtime.h>
#include <math.h>

#define NROWS 4096
#define D 128
#define SPC 8
#define KRET 7
#define MARGIN 0.2f
#define BM 128                // tile rows per block
#define BN 64                 // tile cols per block
#define CTW 32                // cols per wave (selection granularity)
#define NCT (NROWS / CTW)     // 128 col-tiles per row
#define CPR (NCT * KRET)      // 896 candidates per row

typedef unsigned long long u64;
typedef unsigned int u32;
typedef __attribute__((ext_vector_type(8))) short short8;   // 8 bf16 (4 VGPRs)
typedef __attribute__((ext_vector_type(4))) float f32x4;    // MFMA accumulator

__device__ __forceinline__ u32 minu32(u32 a, u32 b) { return a < b ? a : b; }
__device__ __forceinline__ u32 maxu32(u32 a, u32 b) { return a > b ? a : b; }

// bf16 round-to-nearest-even
__device__ __forceinline__ ushort f2bf_rne(float x) {
    unsigned u = __float_as_uint(x);
    unsigned r = (u + 0x7fffu + ((u >> 16) & 1u)) >> 16;
    return (ushort)r;
}

// ws layout (floats):
//   [0..1]               (fallback accums only)
//   [4096 .. 8191]       diag
//   [8192 .. 40959]      posd (4096 x 8 f32, clamped d^2)
//   [40960 .. 106495]    embH  (4096x128 bf16)
//   [106496 .. 172031]   emb1H (4096x128 bf16)
//   [172032 .. 3842047]  cand (u32, 4096 x 896)
//   [3842048 ..]         rowls (4096), rowcnt (4096)

// ---- prep: bf16 round of both matrices + exact f32 Gram diagonal ----
__global__ __launch_bounds__(256) void prep_kernel(const float* __restrict__ emb,
                                                   const float* __restrict__ emb1,
                                                   ushort* __restrict__ embH,
                                                   ushort* __restrict__ emb1H,
                                                   float* __restrict__ diag) {
    const int lane = threadIdx.x & 63;
    const int row = blockIdx.x * 4 + (threadIdx.x >> 6);
    const size_t base = (size_t)row * D + 2 * lane;
    const float2 a = *(const float2*)(emb + base);
    const float2 b = *(const float2*)(emb1 + base);

    *(ushort2*)(embH + base)  = make_ushort2(f2bf_rne(a.x), f2bf_rne(a.y));
    *(ushort2*)(emb1H + base) = make_ushort2(f2bf_rne(b.x), f2bf_rne(b.y));

    float s = a.x * b.x + a.y * b.y;
#pragma unroll
    for (int off = 1; off < 64; off <<= 1) s += __shfl_xor(s, off, 64);
    if (lane == 0) diag[row] = s;
}

// ---- dist: 128x64 tile, 4 waves x (64 rows x 32 cols), K in 4 LDS phases of 32 ----
// LDS: staging AH [128][40] u16 (10240 B) + BH [64][40] (5120 B) inside an 18432 B
// arena that is overlaid after the k-loop by 4 per-wave score bufs [64][36] u16.
// Stride 40 u16 = 80 B: 16B-aligned rows for b128, gcd(20,32)=4 -> 2-way (free) reads.
__global__ __launch_bounds__(256, 6) void dist_mfma(const ushort* __restrict__ embH,
                                                    const ushort* __restrict__ emb1H,
                                                    const int* __restrict__ labels,
                                                    const int* __restrict__ labels1,
                                                    const float* __restrict__ diag,
                                                    float* __restrict__ posd, u32* __restrict__ cand) {
    __shared__ ushort smem[9216];         // 18432 B arena
    __shared__ float sdA[BM], sdB[BN];
    ushort* AH = smem;                    // [128][40]
    ushort* BH = smem + 5120;             // [64][40]

    const int t = threadIdx.x;
    const int i0 = blockIdx.y * BM, j0 = blockIdx.x * BN;
    const int w = t >> 6, l = t & 63;
    const int R = (w >> 1) * 64, C = (w & 1) * 32;
    const int lr = l & 15, lg = l >> 4;

    if (t < BM) sdA[t] = diag[i0 + t];
    else if (t < BM + BN) sdB[t - BM] = diag[j0 + t - BM];

    // wave-uniform positive gate from global labels (range-overlap test, exact superset)
    int la = labels1[i0 + R + l];
    int lb = labels[j0 + C + (l & 31)];
    int mnA = la, mxA = la, mnB = lb, mxB = lb;
#pragma unroll
    for (int off = 1; off < 64; off <<= 1) {
        mnA = min(mnA, __shfl_xor(mnA, off, 64));
        mxA = max(mxA, __shfl_xor(mxA, off, 64));
        mnB = min(mnB, __shfl_xor(mnB, off, 64));
        mxB = max(mxB, __shfl_xor(mxB, off, 64));
    }
    const bool hasPos = !(mxA < mnB || mxB < mnA);

    f32x4 acc[4][2];
#pragma unroll
    for (int m = 0; m < 4; ++m)
#pragma unroll
        for (int n = 0; n < 2; ++n) acc[m][n] = (f32x4){0.f, 0.f, 0.f, 0.f};

    const int arow = t >> 1, ac0 = (t & 1) * 2;   // A: 2 chunks/thread
    const int brow = t >> 2, bc = t & 3;          // B: 1 chunk/thread
    for (int p = 0; p < 4; ++p) {
        if (p) __syncthreads();            // prior frag reads complete before restage
#pragma unroll
        for (int n = 0; n < 2; ++n) {
            const int c = ac0 + n;
            *(uint4*)(AH + arow * 40 + c * 8) =
                *(const uint4*)(embH + (size_t)(i0 + arow) * D + p * 32 + c * 8);
        }
        *(uint4*)(BH + brow * 40 + bc * 8) =
            *(const uint4*)(emb1H + (size_t)(j0 + brow) * D + p * 32 + bc * 8);
        __syncthreads();

        const int ko = lg * 8;
        short8 ah[4], bh[2];
#pragma unroll
        for (int m = 0; m < 4; ++m) ah[m] = *(const short8*)(AH + (R + 16 * m + lr) * 40 + ko);
#pragma unroll
        for (int n = 0; n < 2; ++n) bh[n] = *(const short8*)(BH + (C + 16 * n + lr) * 40 + ko);
#pragma unroll
        for (int m = 0; m < 4; ++m)
#pragma unroll
            for (int n = 0; n < 2; ++n)
                acc[m][n] = __builtin_amdgcn_mfma_f32_16x16x32_bf16(ah[m], bh[n], acc[m][n], 0, 0, 0);
    }

    // preload diag slices (sdA/sdB are not overlaid)
    float sdA_r[16], sdB_c[2];
#pragma unroll
    for (int m = 0; m < 4; ++m)
#pragma unroll
        for (int r = 0; r < 4; ++r) sdA_r[m * 4 + r] = sdA[R + 16 * m + 4 * lg + r];
#pragma unroll
    for (int n = 0; n < 2; ++n) sdB_c[n] = sdB[C + 16 * n + lr];

    int sLi_r[16], sLj_c[2];
    if (hasPos) {   // labels direct from L2-hot global (only ~diagonal blocks)
#pragma unroll
        for (int m = 0; m < 4; ++m)
#pragma unroll
            for (int r = 0; r < 4; ++r) sLi_r[m * 4 + r] = labels1[i0 + R + 16 * m + 4 * lg + r];
#pragma unroll
        for (int n = 0; n < 2; ++n) sLj_c[n] = labels[j0 + C + 16 * n + lr];
    }

    __syncthreads();   // all waves' frag reads done; arena becomes score bufs

    // epilogue: clamped d^2 -> bf16 u16 scores in this wave's [64][36] buffer.
    // C/D layout (m89-verified): col = lane&15, row = (lane>>4)*4 + reg
    ushort* dq = smem + w * 2304;
    if (!hasPos) {
#pragma unroll
        for (int m = 0; m < 4; ++m)
#pragma unroll
            for (int n = 0; n < 2; ++n)
#pragma unroll
                for (int r = 0; r < 4; ++r) {
                    const int row = 16 * m + 4 * lg + r;
                    const int col = 16 * n + lr;
                    const float d2c = fmaxf(sdA_r[m * 4 + r] + sdB_c[n] - 2.f * acc[m][n][r], 1e-4f);
                    dq[row * 36 + col] = f2bf_rne(d2c);
                }
    } else {
#pragma unroll
        for (int m = 0; m < 4; ++m)
#pragma unroll
            for (int n = 0; n < 2; ++n)
#pragma unroll
                for (int r = 0; r < 4; ++r) {
                    const int row = 16 * m + 4 * lg + r;
                    const int col = 16 * n + lr;
                    const int gi = i0 + R + row, gj = j0 + C + col;
                    const float d2c = fmaxf(sdA_r[m * 4 + r] + sdB_c[n] - 2.f * acc[m][n][r], 1e-4f);
                    const bool pos = (sLj_c[n] == sLi_r[m * 4 + r]) && (gi != gj);
                    if (pos) posd[(size_t)gi * SPC + (gj & (SPC - 1))] = d2c;
                    dq[row * 36 + col] = pos ? (ushort)0xFFFFu : f2bf_rne(d2c);
                }
    }

    // wave-local sync: this wave wrote exactly the rows it scans (rule 18 fence)
    asm volatile("s_waitcnt lgkmcnt(0)" ::: "memory");
    __builtin_amdgcn_sched_barrier(0);

    // selection: 1 thread per row over 32 cols; guarded sorted-7 insert (r7-proven).
    // u32 pack (score16|col12): exact (score, col) lex order = reference tie-break.
    {
        u32 s[KRET];
#pragma unroll
        for (int k = 0; k < KRET; ++k) s[k] = 0xFFFFFFFFu;
        const ushort* dr = dq + l * 36;
        const u32 cbase = (u32)(j0 + C);
#pragma unroll 4
        for (int c = 0; c < 32; ++c) {
            const int cc = (c + l) & 31;              // diagonal stagger
            const u32 pk = ((u32)dr[cc] << 16) | (cbase + cc);
            if (pk < s[KRET - 1]) {
                u32 tmp = pk;
#pragma unroll
                for (int k = 0; k < KRET; ++k) {
                    const u32 lo = minu32(s[k], tmp);
                    tmp = maxu32(s[k], tmp);
                    s[k] = lo;
                }
            }
        }
        u32* cw = cand + (size_t)(i0 + R + l) * CPR + (size_t)((j0 + C) >> 5) * KRET;
#pragma unroll
        for (int k = 0; k < KRET; ++k) cw[k] = s[k];
    }
}

// ---- merge 896 u32 candidates/row -> global top-7, validity, loss. Wave per row. ----
__global__ __launch_bounds__(256) void merge_kernel(const float* __restrict__ emb,
                                                    const float* __restrict__ posd,
                                                    const u32* __restrict__ cand,
                                                    float* __restrict__ rowls,
                                                    float* __restrict__ rowcnt) {
    const int lane = threadIdx.x & 63;
    const int i = blockIdx.x * 4 + (threadIdx.x >> 6);
    const u32* cr = cand + (size_t)i * CPR;
    u32 e[14];
#pragma unroll
    for (int q = 0; q < 14; ++q) e[q] = cr[q * 64 + lane];

    u32 w[KRET];
#pragma unroll
    for (int r = 0; r < KRET; ++r) {
        u32 m = e[0];
#pragma unroll
        for (int q = 1; q < 14; ++q) m = minu32(m, e[q]);
#pragma unroll
        for (int off = 1; off < 64; off <<= 1) m = minu32(m, (u32)__shfl_xor((int)m, off, 64));
        w[r] = m;
#pragma unroll
        for (int q = 0; q < 14; ++q) e[q] = (e[q] == m) ? 0xFFFFFFFFu : e[q];
    }

    // sort winners by column index: rotate to (col12 << 20 | score16 << 4), Batcher-8
    u32 s[8];
#pragma unroll
    for (int r = 0; r < KRET; ++r) s[r] = (w[r] << 20) | (w[r] >> 12);
    s[7] = 0xFFFFFFFFu;
#define CE(x, y) { u32 lo = minu32(s[x], s[y]); u32 hi = maxu32(s[x], s[y]); s[x] = lo; s[y] = hi; }
    CE(0,1) CE(2,3) CE(4,5) CE(6,7)
    CE(0,2) CE(1,3) CE(4,6) CE(5,7)
    CE(1,2) CE(5,6)
    CE(0,4) CE(1,5) CE(2,6) CE(3,7)
    CE(2,4) CE(3,5)
    CE(1,2) CE(3,4) CE(5,6)
#undef CE

    const int ig = i & (SPC - 1);
    float ls = 0.f, cnt = 0.f;
    bool any = false;
    bool v[KRET];
    int nidx[KRET];
#pragma unroll
    for (int k = 0; k < KRET; ++k) {
        nidx[k] = (int)(s[k] >> 20);
        const float d2n = __uint_as_float(((s[k] >> 4) & 0xFFFF0u) << 12);  // score16 << 16
        const float dneg = sqrtf(d2n);
        const int m = k + (k >= ig ? 1 : 0);
        const float dp = sqrtf(posd[(size_t)i * SPC + m]);
        v[k] = dp < dneg + MARGIN;       // wave-uniform
        any = any || v[k];
    }

    if (any) {
        const float a0 = emb[(size_t)i * D + lane];
        const float a1 = emb[(size_t)i * D + 64 + lane];
#pragma unroll
        for (int k = 0; k < KRET; ++k) {
            if (v[k]) {
                const int m = k + (k >= ig ? 1 : 0);
                const int tp = (i & ~(SPC - 1)) + m;
                const int tn = nidx[k];
                float d0 = emb[(size_t)tp * D + lane] - a0;
                float d1 = emb[(size_t)tp * D + 64 + lane] - a1;
                float sp = d0 * d0 + d1 * d1;
                float g0 = emb[(size_t)tn * D + lane] - a0;
                float g1 = emb[(size_t)tn * D + 64 + lane] - a1;
                float sn = g0 * g0 + g1 * g1;
#pragma unroll
                for (int off = 1; off < 64; off <<= 1) {
                    sp += __shfl_xor(sp, off, 64);
                    sn += __shfl_xor(sn, off, 64);
                }
                ls += (sqrtf(sp + 1e-8f) + MARGIN) + fmaxf(MARGIN - sqrtf(sn + 1e-8f), 0.f);
                cnt += 1.f;
            }
        }
    }
    if (lane == 0) {           // always write: poison-safe, deterministic, atomic-free
        rowls[i] = ls;
        rowcnt[i] = cnt;
    }
}

// ---- deterministic single-block reduction over 4096 per-row partials ----
__global__ __launch_bounds__(256) void finalize_kernel(const float* __restrict__ rowls,
                                                       const float* __restrict__ rowcnt,
                                                       float* __restrict__ out) {
    const int t = threadIdx.x;
    __shared__ float sls[4], scnt[4];
    float ls = 0.f, cnt = 0.f;
#pragma unroll
    for (int q = 0; q < NROWS / 256; ++q) {
        ls += rowls[q * 256 + t];
        cnt += rowcnt[q * 256 + t];
    }
#pragma unroll
    for (int off = 1; off < 64; off <<= 1) {
        ls += __shfl_xor(ls, off, 64);
        cnt += __shfl_xor(cnt, off, 64);
    }
    if ((t & 63) == 0) { sls[t >> 6] = ls; scnt[t >> 6] = cnt; }
    __syncthreads();
    if (t == 0) {
        float L = sls[0] + sls[1] + sls[2] + sls[3];
        float C = scnt[0] + scnt[1] + scnt[2] + scnt[3];
        out[0] = C > 0.f ? L / C : L;
    }
}

// ---------------- Fallback path (round-1, only if ws too small) ----------------
__global__ __launch_bounds__(256) void diag_kernel(const float* __restrict__ emb,
                                                   const float* __restrict__ emb1,
                                                   float* __restrict__ diag) {
    int wave = threadIdx.x >> 6;
    int lane = threadIdx.x & 63;
    int row = blockIdx.x * 4 + wave;
    const float* a = emb + (size_t)row * D;
    const float* b = emb1 + (size_t)row * D;
    float s = a[lane] * b[lane] + a[lane + 64] * b[lane + 64];
    for (int off = 32; off > 0; off >>= 1) s += __shfl_down(s, off, 64);
    if (lane == 0) diag[row] = s;
}

__global__ __launch_bounds__(256) void main_kernel(const float* __restrict__ emb,
                                                   const float* __restrict__ emb1,
                                                   const int* __restrict__ labels,
                                                   const int* __restrict__ labels1,
                                                   const float* __restrict__ diag,
                                                   float* __restrict__ ws_acc) {
    const int i = blockIdx.x;
    const int tid = threadIdx.x;
    __shared__ float s_anchor[D];
    __shared__ float s_posd[SPC];
    __shared__ u64 s_red[4];
    __shared__ u64 s_win;
    __shared__ int s_negidx[KRET];
    __shared__ float s_negd[KRET];
    __shared__ float s_dreal[2 * KRET];

    if (tid < D) s_anchor[tid] = emb[(size_t)i * D + tid];
    __syncthreads();
    const float diag_i = diag[i];
    const int li = labels1[i];
    float score[16];
#pragma unroll
    for (int it = 0; it < 16; ++it) {
        int j = it * 256 + tid;
        const float4* r = (const float4*)(emb1 + (size_t)j * D);
        float acc = 0.f;
#pragma unroll
        for (int q = 0; q < D / 4; ++q) {
            float4 vv = r[q];
            acc = fmaf(vv.x, s_anchor[4 * q + 0], acc);
            acc = fmaf(vv.y, s_anchor[4 * q + 1], acc);
            acc = fmaf(vv.z, s_anchor[4 * q + 2], acc);
            acc = fmaf(vv.w, s_anchor[4 * q + 3], acc);
        }
        float d2 = diag_i + diag[j] - 2.f * acc;
        float dist = sqrtf(fmaxf(d2, 1e-4f));
        bool is_pos = (labels[j] == li) && (j != i);
        if (is_pos) s_posd[j & (SPC - 1)] = dist;
        score[it] = dist + (is_pos ? 1e6f : 0.f);
    }
    __syncthreads();
    for (int r = 0; r < KRET; ++r) {
        u64 best = ~0ull;
#pragma unroll
        for (int it = 0; it < 16; ++it) {
            u64 p = ((u64)__float_as_uint(score[it]) << 32) | (unsigned)(it * 256 + tid);
            best = best < p ? best : p;
        }
        for (int off = 32; off > 0; off >>= 1) {
            u64 o = __shfl_down(best, off, 64);
            best = best < o ? best : o;
        }
        if ((tid & 63) == 0) s_red[tid >> 6] = best;
        __syncthreads();
        if (tid == 0) {
            u64 w2 = s_red[0];
            w2 = w2 < s_red[1] ? w2 : s_red[1];
            w2 = w2 < s_red[2] ? w2 : s_red[2];
            w2 = w2 < s_red[3] ? w2 : s_red[3];
            s_win = w2;
        }
        __syncthreads();
        u64 w2 = s_win;
        int cj = (int)(w2 & 0xffffffffu);
        if (tid == (cj & 255)) score[cj >> 8] = 1e30f;
        if (tid == 0) { s_negidx[r] = cj; s_negd[r] = __uint_as_float((unsigned)(w2 >> 32)); }
        __syncthreads();
    }
    if (tid == 0) {
        for (int a = 1; a < KRET; ++a) {
            int ix = s_negidx[a]; float dv = s_negd[a];
            int b = a - 1;
            while (b >= 0 && s_negidx[b] > ix) {
                s_negidx[b + 1] = s_negidx[b]; s_negd[b + 1] = s_negd[b]; --b;
            }
            s_negidx[b + 1] = ix; s_negd[b + 1] = dv;
        }
    }
    __syncthreads();
    {
        int wave = tid >> 6, lane = tid & 63;
        int gb = i & ~(SPC - 1);
        for (int p = wave; p < 2 * KRET; p += 4) {
            int tgt;
            if (p < KRET) {
                int k = p;
                int m = k + (k >= (i & (SPC - 1)) ? 1 : 0);
                tgt = gb + m;
            } else tgt = s_negidx[p - KRET];
            float d0 = emb[(size_t)tgt * D + lane] - s_anchor[lane];
            float d1 = emb[(size_t)tgt * D + 64 + lane] - s_anchor[64 + lane];
            float s = d0 * d0 + d1 * d1;
            for (int off = 32; off > 0; off >>= 1) s += __shfl_down(s, off, 64);
            if (lane == 0) s_dreal[p] = sqrtf(s + 1e-8f);
        }
    }
    __syncthreads();
    if (tid == 0) {
        float ls = 0.f, cnt = 0.f;
        for (int k = 0; k < KRET; ++k) {
            int m = k + (k >= (i & (SPC - 1)) ? 1 : 0);
            if (s_posd[m] < s_negd[k] + MARGIN) {
                ls += (s_dreal[k] + MARGIN) + fmaxf(MARGIN - s_dreal[KRET + k], 0.f);
                cnt += 1.f;
            }
        }
        if (ls != 0.f) atomicAdd(&ws_acc[0], ls);
        if (cnt != 0.f) atomicAdd(&ws_acc[1], cnt);
    }
}

__global__ void finalize_ws(const float* __restrict__ ws_acc, float* __restrict__ out) {
    float ls = ws_acc[0], cnt = ws_acc[1];
    out[0] = cnt > 0.f ? ls / cnt : ls;
}

extern "C" void kernel_launch(void* const* d_in, const int* in_sizes, int n_in,
                              void* d_out, int out_size, void* d_ws, size_t ws_size,
                              hipStream_t stream) {
    const float* emb     = (const float*)d_in[0];
    const int*   labels  = (const int*)d_in[1];
    const float* emb1    = (const float*)d_in[2];
    const int*   labels1 = (const int*)d_in[3];
    float* ws = (float*)d_ws;

    const size_t need = (size_t)3850240 * sizeof(float);
    if (ws_size >= need) {
        float*  diag   = ws + 4096;
        float*  posd   = ws + 8192;
        ushort* embH   = (ushort*)(ws + 40960);
        ushort* emb1H  = (ushort*)(ws + 106496);
        u32*    cand   = (u32*)(ws + 172032);
        float*  rowls  = ws + 3842048;
        float*  rowcnt = ws + 3846144;

        prep_kernel<<<NROWS / 4, 256, 0, stream>>>(emb, emb1, embH, emb1H, diag);
        dim3 grid(NROWS / BN, NROWS / BM);     // (64, 32) = 2048 blocks
        dist_mfma<<<grid, 256, 0, stream>>>(embH, emb1H, labels, labels1, diag, posd, cand);
        merge_kernel<<<NROWS / 4, 256, 0, stream>>>(emb, posd, cand, rowls, rowcnt);
        finalize_kernel<<<1, 256, 0, stream>>>(rowls, rowcnt, (float*)d_out);
    } else {
        hipMemsetAsync(d_ws, 0, 2 * sizeof(float), stream);
        float* diag = ws + 2;
        diag_kernel<<<NROWS / 4, 256, 0, stream>>>(emb, emb1, diag);
        main_kernel<<<NROWS, 256, 0, stream>>>(emb, emb1, labels, labels1, diag, ws);
        finalize_ws<<<1, 1, 0, stream>>>(ws, (float*)d_out);
    }
}

// Round 11
// 50.240 us; speedup vs baseline: 1.3124x; 1.0369x over previous
//
#include <hip/hip_runtime.h>
#include <math.h>

#define NROWS 4096
#define D 128
#define SPC 8
#define KRET 7
#define MARGIN 0.2f
#define NTILE 32              // 4096/128 column tiles
#define CPT 14                // candidates per (row, tile): 2 quadrants x top-7
#define CPR (NTILE * CPT)     // 448 candidates per row

typedef unsigned long long u64;
typedef unsigned int u32;
typedef __attribute__((ext_vector_type(8))) short short8;   // 8 bf16 (4 VGPRs)
typedef __attribute__((ext_vector_type(4))) float f32x4;    // MFMA accumulator

__device__ __forceinline__ u32 minu32(u32 a, u32 b) { return a < b ? a : b; }
__device__ __forceinline__ u32 maxu32(u32 a, u32 b) { return a > b ? a : b; }

// bf16 round-to-nearest-even (prep only)
__device__ __forceinline__ ushort f2bf_rne(float x) {
    unsigned u = __float_as_uint(x);
    unsigned r = (u + 0x7fffu + ((u >> 16) & 1u)) >> 16;
    return (ushort)r;
}

// sorted-7 insert chain (14 ops, caller guards)
__device__ __forceinline__ void ins7(u32 (&s)[KRET], u32 pk) {
#pragma unroll
    for (int k = 0; k < KRET; ++k) {
        const u32 lo = minu32(s[k], pk);
        pk = maxu32(s[k], pk);
        s[k] = lo;
    }
}

// ws layout (floats):
//   [0..1]               (fallback accums only)
//   [4096 .. 8191]       diag
//   [8192 .. 40959]      posd (4096 x 8 f32, stores clamped d^2)
//   [40960 .. 106495]    embH  (4096x128 bf16)
//   [106496 .. 172031]   emb1H (4096x128 bf16)
//   [172032 .. 2007039]  cand (u32, 4096 x 448)
//   [2007040 ..]         rowls (4096), rowcnt (4096)

// ---- prep: bf16 round of both matrices + exact f32 Gram diagonal ----
__global__ __launch_bounds__(256) void prep_kernel(const float* __restrict__ emb,
                                                   const float* __restrict__ emb1,
                                                   ushort* __restrict__ embH,
                                                   ushort* __restrict__ emb1H,
                                                   float* __restrict__ diag) {
    const int lane = threadIdx.x & 63;
    const int row = blockIdx.x * 4 + (threadIdx.x >> 6);
    const size_t base = (size_t)row * D + 2 * lane;
    const float2 a = *(const float2*)(emb + base);
    const float2 b = *(const float2*)(emb1 + base);

    *(ushort2*)(embH + base)  = make_ushort2(f2bf_rne(a.x), f2bf_rne(a.y));
    *(ushort2*)(emb1H + base) = make_ushort2(f2bf_rne(b.x), f2bf_rne(b.y));

    float s = a.x * b.x + a.y * b.y;
#pragma unroll
    for (int off = 1; off < 64; off <<= 1) s += __shfl_xor(s, off, 64);
    if (lane == 0) diag[row] = s;
}

// ---- dist tile via bf16 MFMA + fused per-quadrant top-7 (d^2-space, u32-packed) ----
// 128x128 tile, 4 waves, each wave owns a 64x64 quadrant (R,C).  [r7 structure]
__global__ __launch_bounds__(256, 4) void dist_mfma(const ushort* __restrict__ embH,
                                                    const ushort* __restrict__ emb1H,
                                                    const int* __restrict__ labels,
                                                    const int* __restrict__ labels1,
                                                    const float* __restrict__ diag,
                                                    float* __restrict__ posd, u32* __restrict__ cand) {
    __shared__ ushort smem[2][9216];      // AH, BH: [128][72] bf16 each
    __shared__ float sdA[128], sdB[128];
    __shared__ int sLi[128], sLj[128];
    __shared__ int s_lmin[4], s_lmax[4];
    ushort* AH = smem[0];
    ushort* BH = smem[1];
    ushort* distbuf = (ushort*)(void*)smem;   // [128][132] u16 trunc-bf16(d2) scores, overlays staging

    const int t = threadIdx.x;
    const int i0 = blockIdx.y * 128, j0 = blockIdx.x * 128;
    const int w = t >> 6, l = t & 63;

    {   // diag + labels -> LDS, plus per-wave label min/max for block-uniform pos gating
        int lab;
        if (t < 128) { sdA[t] = diag[i0 + t]; lab = labels1[i0 + t]; sLi[t] = lab; }
        else         { sdB[t - 128] = diag[j0 + t - 128]; lab = labels[j0 + t - 128]; sLj[t - 128] = lab; }
        int mn = lab, mx = lab;
#pragma unroll
        for (int off = 1; off < 64; off <<= 1) {
            mn = min(mn, __shfl_xor(mn, off, 64));
            mx = max(mx, __shfl_xor(mx, off, 64));
        }
        if (l == 0) { s_lmin[w] = mn; s_lmax[w] = mx; }
    }

    const int R = (w >> 1) * 64, C = (w & 1) * 64;
    const int lr = l & 15, lg = l >> 4;

    f32x4 acc[4][4];
#pragma unroll
    for (int m = 0; m < 4; ++m)
#pragma unroll
        for (int n = 0; n < 4; ++n) acc[m][n] = (f32x4){0.f, 0.f, 0.f, 0.f};

    bool hasPos = false;
    const int srow = t & 127;
    for (int p = 0; p < 2; ++p) {
        if (p) __syncthreads();            // phase-0 frag reads complete before restage
#pragma unroll
        for (int n = 0; n < 4; ++n) {
            const int c = n * 2 + (t >> 7);                         // 0..7
            const size_t gA = (size_t)(i0 + srow) * D + p * 64 + c * 8;
            const size_t gB = (size_t)(j0 + srow) * D + p * 64 + c * 8;
            const int ld = srow * 72 + c * 8;
            *(uint4*)(AH + ld) = *(const uint4*)(embH + gA);
            *(uint4*)(BH + ld) = *(const uint4*)(emb1H + gB);
        }
        __syncthreads();

        if (p == 0) {   // labels/diag now visible: block-uniform pos gate
            const int minLi = min(s_lmin[0], s_lmin[1]);
            const int maxLi = max(s_lmax[0], s_lmax[1]);
            const int minLj = min(s_lmin[2], s_lmin[3]);
            const int maxLj = max(s_lmax[2], s_lmax[3]);
            hasPos = !(maxLi < minLj || maxLj < minLi);
        }

#pragma unroll
        for (int ks = 0; ks < 2; ++ks) {
            const int koff = ks * 32 + lg * 8;
            short8 ah[4], bh[4];
#pragma unroll
            for (int m = 0; m < 4; ++m) {
                ah[m] = *(const short8*)(AH + (R + 16 * m + lr) * 72 + koff);
                bh[m] = *(const short8*)(BH + (C + 16 * m + lr) * 72 + koff);
            }
#pragma unroll
            for (int m = 0; m < 4; ++m)
#pragma unroll
                for (int n = 0; n < 4; ++n)
                    acc[m][n] = __builtin_amdgcn_mfma_f32_16x16x32_bf16(ah[m], bh[n], acc[m][n], 0, 0, 0);
        }
    }

    // preload diag slices to registers (sdA/sdB are NOT overlaid; safe across barrier)
    float sdA_r[16], sdB_c[4];
#pragma unroll
    for (int m = 0; m < 4; ++m)
#pragma unroll
        for (int r = 0; r < 4; ++r) sdA_r[m * 4 + r] = sdA[R + 16 * m + 4 * lg + r];
#pragma unroll
    for (int n = 0; n < 4; ++n) sdB_c[n] = sdB[C + 16 * n + lr];

    __syncthreads();   // all waves' frag reads done; staging area becomes score buf

    // epilogue: clamped d^2 -> TRUNCATED bf16 u16 scores in distbuf (monotone pack).
    // C/D layout (m89-verified): col = lane&15, row = (lane>>4)*4 + reg
    if (!hasPos) {
#pragma unroll
        for (int m = 0; m < 4; ++m)
#pragma unroll
            for (int n = 0; n < 4; ++n)
#pragma unroll
                for (int r = 0; r < 4; ++r) {
                    const int row = R + 16 * m + 4 * lg + r;
                    const int col = C + 16 * n + lr;
                    const float d2c = fmaxf(sdA_r[m * 4 + r] + sdB_c[n] - 2.f * acc[m][n][r], 1e-4f);
                    distbuf[row * 132 + col] = (ushort)(__float_as_uint(d2c) >> 16);
                }
    } else {
        int sLi_r[16], sLj_c[4];
#pragma unroll
        for (int m = 0; m < 4; ++m)
#pragma unroll
            for (int r = 0; r < 4; ++r) sLi_r[m * 4 + r] = sLi[R + 16 * m + 4 * lg + r];
#pragma unroll
        for (int n = 0; n < 4; ++n) sLj_c[n] = sLj[C + 16 * n + lr];
#pragma unroll
        for (int m = 0; m < 4; ++m)
#pragma unroll
            for (int n = 0; n < 4; ++n)
#pragma unroll
                for (int r = 0; r < 4; ++r) {
                    const int row = R + 16 * m + 4 * lg + r;
                    const int col = C + 16 * n + lr;
                    const int gi = i0 + row, gj = j0 + col;
                    const float d2c = fmaxf(sdA_r[m * 4 + r] + sdB_c[n] - 2.f * acc[m][n][r], 1e-4f);
                    const bool pos = (sLj_c[n] == sLi_r[m * 4 + r]) && (gi != gj);
                    if (pos) posd[(size_t)gi * SPC + (gj & (SPC - 1))] = d2c;
                    distbuf[row * 132 + col] = pos ? (ushort)0xFFFFu
                                                   : (ushort)(__float_as_uint(d2c) >> 16);
                }
    }

    // wave-local sync: this wave's score writes cover exactly the quadrant it scans
    asm volatile("s_waitcnt lgkmcnt(0)" ::: "memory");
    __builtin_amdgcn_sched_barrier(0);

    // selection: 1 thread per row over this wave's 64 cols.
    // 4-way ILP tournament: 4 independent sorted-7 lists (breaks the serial insert
    // chain into 4 parallel streams), merged at the end. Union of per-subset top-7s
    // contains the global top-7; u32 pack keeps exact (score,col) lex tie-break.
    {
        const int row = R + l;
        u32 s0[KRET], s1[KRET], s2[KRET], s3[KRET];
#pragma unroll
        for (int k = 0; k < KRET; ++k) { s0[k] = ~0u; s1[k] = ~0u; s2[k] = ~0u; s3[k] = ~0u; }
        const ushort* dr = distbuf + row * 132 + C;
        const u32 cbase = (u32)(j0 + C);
#pragma unroll 4
        for (int c = 0; c < 64; c += 4) {
            const int b0 = (c + 0 + row) & 63;        // diagonal stagger (bank spread)
            const int b1 = (c + 1 + row) & 63;
            const int b2 = (c + 2 + row) & 63;
            const int b3 = (c + 3 + row) & 63;
            const u32 p0 = ((u32)dr[b0] << 16) | (cbase + b0);
            const u32 p1 = ((u32)dr[b1] << 16) | (cbase + b1);
            const u32 p2 = ((u32)dr[b2] << 16) | (cbase + b2);
            const u32 p3 = ((u32)dr[b3] << 16) | (cbase + b3);
            if (p0 < s0[KRET - 1]) ins7(s0, p0);
            if (p1 < s1[KRET - 1]) ins7(s1, p1);
            if (p2 < s2[KRET - 1]) ins7(s2, p2);
            if (p3 < s3[KRET - 1]) ins7(s3, p3);
        }
        // merge the four lists (21 guarded inserts)
#pragma unroll
        for (int k = 0; k < KRET; ++k) if (s1[k] < s0[KRET - 1]) ins7(s0, s1[k]);
#pragma unroll
        for (int k = 0; k < KRET; ++k) if (s2[k] < s0[KRET - 1]) ins7(s0, s2[k]);
#pragma unroll
        for (int k = 0; k < KRET; ++k) if (s3[k] < s0[KRET - 1]) ins7(s0, s3[k]);

        u32* cw = cand + (size_t)(i0 + row) * CPR + (j0 >> 7) * CPT + (C >> 6) * KRET;
#pragma unroll
        for (int k = 0; k < KRET; ++k) cw[k] = s0[k];
    }
}

// ---- merge 448 u32 candidates/row -> global top-7, validity, loss. Wave per row. ----
__global__ __launch_bounds__(256) void merge_kernel(const float* __restrict__ emb,
                                                    const float* __restrict__ posd,
                                                    const u32* __restrict__ cand,
                                                    float* __restrict__ rowls,
                                                    float* __restrict__ rowcnt) {
    const int lane = threadIdx.x & 63;
    const int i = blockIdx.x * 4 + (threadIdx.x >> 6);
    const u32* cr = cand + (size_t)i * CPR;
    u32 e[7];
#pragma unroll
    for (int q = 0; q < 7; ++q) e[q] = cr[q * 64 + lane];

    u32 w[KRET];
#pragma unroll
    for (int r = 0; r < KRET; ++r) {
        u32 m = e[0];
#pragma unroll
        for (int q = 1; q < 7; ++q) m = minu32(m, e[q]);
#pragma unroll
        for (int off = 1; off < 64; off <<= 1) m = minu32(m, (u32)__shfl_xor((int)m, off, 64));
        w[r] = m;
#pragma unroll
        for (int q = 0; q < 7; ++q) e[q] = (e[q] == m) ? 0xFFFFFFFFu : e[q];
    }

    // sort winners by column index: rotate to (col12 << 20 | score16 << 4), Batcher-8
    u32 s[8];
#pragma unroll
    for (int r = 0; r < KRET; ++r) s[r] = (w[r] << 20) | (w[r] >> 12);
    s[7] = 0xFFFFFFFFu;
#define CE(x, y) { u32 lo = minu32(s[x], s[y]); u32 hi = maxu32(s[x], s[y]); s[x] = lo; s[y] = hi; }
    CE(0,1) CE(2,3) CE(4,5) CE(6,7)
    CE(0,2) CE(1,3) CE(4,6) CE(5,7)
    CE(1,2) CE(5,6)
    CE(0,4) CE(1,5) CE(2,6) CE(3,7)
    CE(2,4) CE(3,5)
    CE(1,2) CE(3,4) CE(5,6)
#undef CE

    const int ig = i & (SPC - 1);
    float ls = 0.f, cnt = 0.f;
    bool any = false;
    bool v[KRET];
    int nidx[KRET];
#pragma unroll
    for (int k = 0; k < KRET; ++k) {
        nidx[k] = (int)(s[k] >> 20);
        const float d2n = __uint_as_float(((s[k] >> 4) & 0xFFFF0u) << 12);  // score16 << 16
        const float dneg = sqrtf(d2n);
        const int m = k + (k >= ig ? 1 : 0);
        const float dp = sqrtf(posd[(size_t)i * SPC + m]);
        v[k] = dp < dneg + MARGIN;       // wave-uniform
        any = any || v[k];
    }

    if (any) {
        const float a0 = emb[(size_t)i * D + lane];
        const float a1 = emb[(size_t)i * D + 64 + lane];
#pragma unroll
        for (int k = 0; k < KRET; ++k) {
            if (v[k]) {
                const int m = k + (k >= ig ? 1 : 0);
                const int tp = (i & ~(SPC - 1)) + m;
                const int tn = nidx[k];
                float d0 = emb[(size_t)tp * D + lane] - a0;
                float d1 = emb[(size_t)tp * D + 64 + lane] - a1;
                float sp = d0 * d0 + d1 * d1;
                float g0 = emb[(size_t)tn * D + lane] - a0;
                float g1 = emb[(size_t)tn * D + 64 + lane] - a1;
                float sn = g0 * g0 + g1 * g1;
#pragma unroll
                for (int off = 1; off < 64; off <<= 1) {
                    sp += __shfl_xor(sp, off, 64);
                    sn += __shfl_xor(sn, off, 64);
                }
                ls += (sqrtf(sp + 1e-8f) + MARGIN) + fmaxf(MARGIN - sqrtf(sn + 1e-8f), 0.f);
                cnt += 1.f;
            }
        }
    }
    if (lane == 0) {           // always write: poison-safe, deterministic
        rowls[i] = ls;
        rowcnt[i] = cnt;
    }
}

// ---- deterministic single-block reduction over 4096 per-row partials ----
__global__ __launch_bounds__(256) void finalize_kernel(const float* __restrict__ rowls,
                                                       const float* __restrict__ rowcnt,
                                                       float* __restrict__ out) {
    const int t = threadIdx.x;
    __shared__ float sls[4], scnt[4];
    float ls = 0.f, cnt = 0.f;
#pragma unroll
    for (int q = 0; q < NROWS / 256; ++q) {
        ls += rowls[q * 256 + t];
        cnt += rowcnt[q * 256 + t];
    }
#pragma unroll
    for (int off = 1; off < 64; off <<= 1) {
        ls += __shfl_xor(ls, off, 64);
        cnt += __shfl_xor(cnt, off, 64);
    }
    if ((t & 63) == 0) { sls[t >> 6] = ls; scnt[t >> 6] = cnt; }
    __syncthreads();
    if (t == 0) {
        float L = sls[0] + sls[1] + sls[2] + sls[3];
        float C = scnt[0] + scnt[1] + scnt[2] + scnt[3];
        out[0] = C > 0.f ? L / C : L;
    }
}

// ---------------- Fallback path (round-1, only if ws too small) ----------------
__global__ __launch_bounds__(256) void diag_kernel(const float* __restrict__ emb,
                                                   const float* __restrict__ emb1,
                                                   float* __restrict__ diag) {
    int wave = threadIdx.x >> 6;
    int lane = threadIdx.x & 63;
    int row = blockIdx.x * 4 + wave;
    const float* a = emb + (size_t)row * D;
    const float* b = emb1 + (size_t)row * D;
    float s = a[lane] * b[lane] + a[lane + 64] * b[lane + 64];
    for (int off = 32; off > 0; off >>= 1) s += __shfl_down(s, off, 64);
    if (lane == 0) diag[row] = s;
}

__global__ __launch_bounds__(256) void main_kernel(const float* __restrict__ emb,
                                                   const float* __restrict__ emb1,
                                                   const int* __restrict__ labels,
                                                   const int* __restrict__ labels1,
                                                   const float* __restrict__ diag,
                                                   float* __restrict__ ws_acc) {
    const int i = blockIdx.x;
    const int tid = threadIdx.x;
    __shared__ float s_anchor[D];
    __shared__ float s_posd[SPC];
    __shared__ u64 s_red[4];
    __shared__ u64 s_win;
    __shared__ int s_negidx[KRET];
    __shared__ float s_negd[KRET];
    __shared__ float s_dreal[2 * KRET];

    if (tid < D) s_anchor[tid] = emb[(size_t)i * D + tid];
    __syncthreads();
    const float diag_i = diag[i];
    const int li = labels1[i];
    float score[16];
#pragma unroll
    for (int it = 0; it < 16; ++it) {
        int j = it * 256 + tid;
        const float4* r = (const float4*)(emb1 + (size_t)j * D);
        float acc = 0.f;
#pragma unroll
        for (int q = 0; q < D / 4; ++q) {
            float4 vv = r[q];
            acc = fmaf(vv.x, s_anchor[4 * q + 0], acc);
            acc = fmaf(vv.y, s_anchor[4 * q + 1], acc);
            acc = fmaf(vv.z, s_anchor[4 * q + 2], acc);
            acc = fmaf(vv.w, s_anchor[4 * q + 3], acc);
        }
        float d2 = diag_i + diag[j] - 2.f * acc;
        float dist = sqrtf(fmaxf(d2, 1e-4f));
        bool is_pos = (labels[j] == li) && (j != i);
        if (is_pos) s_posd[j & (SPC - 1)] = dist;
        score[it] = dist + (is_pos ? 1e6f : 0.f);
    }
    __syncthreads();
    for (int r = 0; r < KRET; ++r) {
        u64 best = ~0ull;
#pragma unroll
        for (int it = 0; it < 16; ++it) {
            u64 p = ((u64)__float_as_uint(score[it]) << 32) | (unsigned)(it * 256 + tid);
            best = best < p ? best : p;
        }
        for (int off = 32; off > 0; off >>= 1) {
            u64 o = __shfl_down(best, off, 64);
            best = best < o ? best : o;
        }
        if ((tid & 63) == 0) s_red[tid >> 6] = best;
        __syncthreads();
        if (tid == 0) {
            u64 w2 = s_red[0];
            w2 = w2 < s_red[1] ? w2 : s_red[1];
            w2 = w2 < s_red[2] ? w2 : s_red[2];
            w2 = w2 < s_red[3] ? w2 : s_red[3];
            s_win = w2;
        }
        __syncthreads();
        u64 w2 = s_win;
        int cj = (int)(w2 & 0xffffffffu);
        if (tid == (cj & 255)) score[cj >> 8] = 1e30f;
        if (tid == 0) { s_negidx[r] = cj; s_negd[r] = __uint_as_float((unsigned)(w2 >> 32)); }
        __syncthreads();
    }
    if (tid == 0) {
        for (int a = 1; a < KRET; ++a) {
            int ix = s_negidx[a]; float dv = s_negd[a];
            int b = a - 1;
            while (b >= 0 && s_negidx[b] > ix) {
                s_negidx[b + 1] = s_negidx[b]; s_negd[b + 1] = s_negd[b]; --b;
            }
            s_negidx[b + 1] = ix; s_negd[b + 1] = dv;
        }
    }
    __syncthreads();
    {
        int wave = tid >> 6, lane = tid & 63;
        int gb = i & ~(SPC - 1);
        for (int p = wave; p < 2 * KRET; p += 4) {
            int tgt;
            if (p < KRET) {
                int k = p;
                int m = k + (k >= (i & (SPC - 1)) ? 1 : 0);
                tgt = gb + m;
            } else tgt = s_negidx[p - KRET];
            float d0 = emb[(size_t)tgt * D + lane] - s_anchor[lane];
            float d1 = emb[(size_t)tgt * D + 64 + lane] - s_anchor[64 + lane];
            float s = d0 * d0 + d1 * d1;
            for (int off = 32; off > 0; off >>= 1) s += __shfl_down(s, off, 64);
            if (lane == 0) s_dreal[p] = sqrtf(s + 1e-8f);
        }
    }
    __syncthreads();
    if (tid == 0) {
        float ls = 0.f, cnt = 0.f;
        for (int k = 0; k < KRET; ++k) {
            int m = k + (k >= (i & (SPC - 1)) ? 1 : 0);
            if (s_posd[m] < s_negd[k] + MARGIN) {
                ls += (s_dreal[k] + MARGIN) + fmaxf(MARGIN - s_dreal[KRET + k], 0.f);
                cnt += 1.f;
            }
        }
        if (ls != 0.f) atomicAdd(&ws_acc[0], ls);
        if (cnt != 0.f) atomicAdd(&ws_acc[1], cnt);
    }
}

__global__ void finalize_ws(const float* __restrict__ ws_acc, float* __restrict__ out) {
    float ls = ws_acc[0], cnt = ws_acc[1];
    out[0] = cnt > 0.f ? ls / cnt : ls;
}

extern "C" void kernel_launch(void* const* d_in, const int* in_sizes, int n_in,
                              void* d_out, int out_size, void* d_ws, size_t ws_size,
                              hipStream_t stream) {
    const float* emb     = (const float*)d_in[0];
    const int*   labels  = (const int*)d_in[1];
    const float* emb1    = (const float*)d_in[2];
    const int*   labels1 = (const int*)d_in[3];
    float* ws = (float*)d_ws;

    const size_t need = (size_t)2015232 * sizeof(float);
    if (ws_size >= need) {
        float*  diag   = ws + 4096;
        float*  posd   = ws + 8192;
        ushort* embH   = (ushort*)(ws + 40960);
        ushort* emb1H  = (ushort*)(ws + 106496);
        u32*    cand   = (u32*)(ws + 172032);
        float*  rowls  = ws + 2007040;
        float*  rowcnt = ws + 2011136;

        prep_kernel<<<NROWS / 4, 256, 0, stream>>>(emb, emb1, embH, emb1H, diag);
        dim3 grid(NROWS / 128, NROWS / 128);
        dist_mfma<<<grid, 256, 0, stream>>>(embH, emb1H, labels, labels1, diag, posd, cand);
        merge_kernel<<<NROWS / 4, 256, 0, stream>>>(emb, posd, cand, rowls, rowcnt);
        finalize_kernel<<<1, 256, 0, stream>>>(rowls, rowcnt, (float*)d_out);
    } else {
        hipMemsetAsync(d_ws, 0, 2 * sizeof(float), stream);
        float* diag = ws + 2;
        diag_kernel<<<NROWS / 4, 256, 0, stream>>>(emb, emb1, diag);
        main_kernel<<<NROWS, 256, 0, stream>>>(emb, emb1, labels, labels1, diag, ws);
        finalize_ws<<<1, 1, 0, stream>>>(ws, (float*)d_out);
    }
}

// Round 12
// 39.236 us; speedup vs baseline: 1.6804x; 1.2805x over previous
//
#include <hip/hip_runtime.h>
#include <math.h>

#define NROWS 4096
#define D 128
#define SPC 8
#define KRET 7
#define MARGIN 0.2f
#define NTILE 32              // 4096/128 column tiles (one per block-col)
#define CPR (NTILE * KRET)    // 224 candidates per row (7 per block)

typedef unsigned long long u64;
typedef unsigned int u32;
typedef __attribute__((ext_vector_type(8))) short short8;    // 8 bf16 (4 VGPRs)
typedef __attribute__((ext_vector_type(16))) float f32x16;   // 32x32 MFMA accumulator

__device__ __forceinline__ u32 minu32(u32 a, u32 b) { return a < b ? a : b; }
__device__ __forceinline__ u32 maxu32(u32 a, u32 b) { return a > b ? a : b; }

// bf16 round-to-nearest-even (prep only)
__device__ __forceinline__ ushort f2bf_rne(float x) {
    unsigned u = __float_as_uint(x);
    unsigned r = (u + 0x7fffu + ((u >> 16) & 1u)) >> 16;
    return (ushort)r;
}

// guarded sorted-7 single insert (14 ops)
__device__ __forceinline__ void ins7(u32 (&s)[KRET], u32 pk) {
#pragma unroll
    for (int k = 0; k < KRET; ++k) {
        const u32 lo = minu32(s[k], pk);
        pk = maxu32(s[k], pk);
        s[k] = lo;
    }
}

// dual insert of sorted pair (q0<=q1) into sorted-7 (r8-validated formula; uses old s)
__device__ __forceinline__ void ins7x2(u32 (&s)[KRET], u32 q0, u32 q1) {
    s[6] = minu32(s[6], minu32(maxu32(s[5], q0), maxu32(s[4], q1)));
    s[5] = minu32(s[5], minu32(maxu32(s[4], q0), maxu32(s[3], q1)));
    s[4] = minu32(s[4], minu32(maxu32(s[3], q0), maxu32(s[2], q1)));
    s[3] = minu32(s[3], minu32(maxu32(s[2], q0), maxu32(s[1], q1)));
    s[2] = minu32(s[2], minu32(maxu32(s[1], q0), maxu32(s[0], q1)));
    s[1] = minu32(s[1], minu32(maxu32(s[0], q0), q1));
    s[0] = minu32(s[0], q0);
}

// ws layout (floats):
//   [0..1]               (fallback accums only)
//   [4096 .. 8191]       diag
//   [8192 .. 40959]      posd (4096 x 8 f32, stores clamped d^2)
//   [40960 .. 106495]    embH  (4096x128 bf16)
//   [106496 .. 172031]   emb1H (4096x128 bf16)
//   [172032 .. 1089535]  cand (u32, 4096 x 224)
//   [2007040 ..]         rowls (4096), rowcnt (4096)

// ---- prep: bf16 round of both matrices + exact f32 Gram diagonal ----
__global__ __launch_bounds__(256) void prep_kernel(const float* __restrict__ emb,
                                                   const float* __restrict__ emb1,
                                                   ushort* __restrict__ embH,
                                                   ushort* __restrict__ emb1H,
                                                   float* __restrict__ diag) {
    const int lane = threadIdx.x & 63;
    const int row = blockIdx.x * 4 + (threadIdx.x >> 6);
    const size_t base = (size_t)row * D + 2 * lane;
    const float2 a = *(const float2*)(emb + base);
    const float2 b = *(const float2*)(emb1 + base);

    *(ushort2*)(embH + base)  = make_ushort2(f2bf_rne(a.x), f2bf_rne(a.y));
    *(ushort2*)(emb1H + base) = make_ushort2(f2bf_rne(b.x), f2bf_rne(b.y));

    float s = a.x * b.x + a.y * b.y;
#pragma unroll
    for (int off = 1; off < 64; off <<= 1) s += __shfl_xor(s, off, 64);
    if (lane == 0) diag[row] = s;
}

// ---- dist: 128x128 tile, 32x32x16 MFMA with SWAPPED operands ----
// D'[j][i]: C/D col = lane&31 -> anchor row i FIXED per lane; regs hold 16 j's/tile.
// Each wave: 32 i's x 128 j's, selection fully in registers (no score LDS, no extra barrier).
__global__ __launch_bounds__(256, 4) void dist_mfma(const ushort* __restrict__ embH,
                                                    const ushort* __restrict__ emb1H,
                                                    const int* __restrict__ labels,
                                                    const int* __restrict__ labels1,
                                                    const float* __restrict__ diag,
                                                    float* __restrict__ posd, u32* __restrict__ cand) {
    __shared__ ushort smem[2][9216];      // AH (emb rows), BH (emb1 rows): [128][72] bf16
    __shared__ float sdA[128], sdB[128];
    __shared__ int sLi[128], sLj[128];
    __shared__ int s_lmin[4], s_lmax[4];
    ushort* AH = smem[0];
    ushort* BH = smem[1];

    const int t = threadIdx.x;
    const int i0 = blockIdx.y * 128, j0 = blockIdx.x * 128;
    const int w = t >> 6, l = t & 63;

    {   // diag + labels -> LDS, plus per-wave label min/max for block-uniform pos gating
        int lab;
        if (t < 128) { sdA[t] = diag[i0 + t]; lab = labels1[i0 + t]; sLi[t] = lab; }
        else         { sdB[t - 128] = diag[j0 + t - 128]; lab = labels[j0 + t - 128]; sLj[t - 128] = lab; }
        int mn = lab, mx = lab;
#pragma unroll
        for (int off = 1; off < 64; off <<= 1) {
            mn = min(mn, __shfl_xor(mn, off, 64));
            mx = max(mx, __shfl_xor(mx, off, 64));
        }
        if (l == 0) { s_lmin[w] = mn; s_lmax[w] = mx; }
    }

    const int il = l & 31;            // lane's i within wave (C/D col)
    const int hi = l >> 5;            // j-half select (C/D row +4*hi)
    const int irow = w * 32 + il;     // block-local anchor row

    f32x16 acc[4];
#pragma unroll
    for (int n = 0; n < 4; ++n)
#pragma unroll
        for (int r = 0; r < 16; ++r) acc[n][r] = 0.f;

    bool hasPos = false;
    const int srow = t & 127;
    for (int p = 0; p < 2; ++p) {
        if (p) __syncthreads();            // phase-0 frag reads complete before restage
#pragma unroll
        for (int n = 0; n < 4; ++n) {
            const int c = n * 2 + (t >> 7);                         // 0..7
            const size_t gA = (size_t)(i0 + srow) * D + p * 64 + c * 8;
            const size_t gB = (size_t)(j0 + srow) * D + p * 64 + c * 8;
            const int ld = srow * 72 + c * 8;
            *(uint4*)(AH + ld) = *(const uint4*)(embH + gA);
            *(uint4*)(BH + ld) = *(const uint4*)(emb1H + gB);
        }
        __syncthreads();

        if (p == 0) {   // labels/diag now visible: block-uniform pos gate
            const int minLi = min(s_lmin[0], s_lmin[1]);
            const int maxLi = max(s_lmax[0], s_lmax[1]);
            const int minLj = min(s_lmin[2], s_lmin[3]);
            const int maxLj = max(s_lmax[2], s_lmax[3]);
            hasPos = !(maxLi < minLj || maxLj < minLi);
        }

        // 4 K-steps of 16 per phase; A-operand = emb1 (j rows), B-operand = emb (i rows)
#pragma unroll
        for (int kk = 0; kk < 4; ++kk) {
            const int ko = kk * 16 + hi * 8;       // frag k-split: 8*(lane>>5)
            const short8 bfr = *(const short8*)(AH + irow * 72 + ko);
#pragma unroll
            for (int n = 0; n < 4; ++n) {
                const short8 afr = *(const short8*)(BH + (n * 32 + il) * 72 + ko);
                acc[n] = __builtin_amdgcn_mfma_f32_32x32x16_bf16(afr, bfr, acc[n], 0, 0, 0);
            }
        }
    }
    // NO further barrier: selection is register-resident; sdA/sdB/sLi/sLj stay valid.

    const float di = sdA[irow];
    const int gi = i0 + irow;
    const int li = hasPos ? sLi[irow] : 0;

    u32 s[KRET];
#pragma unroll
    for (int k = 0; k < KRET; ++k) s[k] = 0xFFFFFFFFu;

#pragma unroll
    for (int n = 0; n < 4; ++n) {
        // j_local = 32n + 8g + 4*hi + q  (g = reg>>2, q = reg&3)
#pragma unroll
        for (int g = 0; g < 4; ++g) {
            const int jb = n * 32 + 8 * g + 4 * hi;
            const float4 dj4 = *(const float4*)(sdB + jb);
            const float djv[4] = {dj4.x, dj4.y, dj4.z, dj4.w};
            u32 pk[4];
            if (!hasPos) {
#pragma unroll
                for (int q = 0; q < 4; ++q) {
                    const int r = g * 4 + q;
                    const float d2c = fmaxf(fmaf(-2.f, acc[n][r], di + djv[q]), 1e-4f);
                    pk[q] = (__float_as_uint(d2c) & 0xFFFF0000u) | (u32)(j0 + jb + q);
                }
            } else {
                const int4 lj4 = *(const int4*)(sLj + jb);
                const int ljv[4] = {lj4.x, lj4.y, lj4.z, lj4.w};
#pragma unroll
                for (int q = 0; q < 4; ++q) {
                    const int r = g * 4 + q;
                    const int gj = j0 + jb + q;
                    const float d2c = fmaxf(fmaf(-2.f, acc[n][r], di + djv[q]), 1e-4f);
                    const bool pos = (ljv[q] == li) && (gi != gj);
                    if (pos) posd[(size_t)gi * SPC + (gj & (SPC - 1))] = d2c;
                    pk[q] = (pos ? 0xFFFF0000u : (__float_as_uint(d2c) & 0xFFFF0000u)) | (u32)gj;
                }
            }
            // two sorted-pair dual inserts
            {
                const u32 q0 = minu32(pk[0], pk[1]), q1 = maxu32(pk[0], pk[1]);
                if (q0 < s[KRET - 1]) ins7x2(s, q0, q1);
            }
            {
                const u32 q0 = minu32(pk[2], pk[3]), q1 = maxu32(pk[2], pk[3]);
                if (q0 < s[KRET - 1]) ins7x2(s, q0, q1);
            }
        }
    }

    // merge the two lane-halves of each row (exchange originals first, then insert)
    u32 o[KRET];
#pragma unroll
    for (int k = 0; k < KRET; ++k) o[k] = (u32)__shfl_xor((int)s[k], 32, 64);
#pragma unroll
    for (int k = 0; k < KRET; ++k) if (o[k] < s[KRET - 1]) ins7(s, o[k]);

    if (hi == 0) {
        u32* cw = cand + (size_t)gi * CPR + (j0 >> 7) * KRET;
#pragma unroll
        for (int k = 0; k < KRET; ++k) cw[k] = s[k];
    }
}

// ---- merge 224 u32 candidates/row -> global top-7, validity, loss. Wave per row. ----
__global__ __launch_bounds__(256) void merge_kernel(const float* __restrict__ emb,
                                                    const float* __restrict__ posd,
                                                    const u32* __restrict__ cand,
                                                    float* __restrict__ rowls,
                                                    float* __restrict__ rowcnt) {
    const int lane = threadIdx.x & 63;
    const int i = blockIdx.x * 4 + (threadIdx.x >> 6);
    const u32* cr = cand + (size_t)i * CPR;
    u32 e[4];
    e[0] = cr[lane];
    e[1] = cr[64 + lane];
    e[2] = cr[128 + lane];
    e[3] = (lane < CPR - 192) ? cr[192 + lane] : 0xFFFFFFFFu;

    u32 w[KRET];
#pragma unroll
    for (int r = 0; r < KRET; ++r) {
        u32 m = minu32(minu32(e[0], e[1]), minu32(e[2], e[3]));
#pragma unroll
        for (int off = 1; off < 64; off <<= 1) m = minu32(m, (u32)__shfl_xor((int)m, off, 64));
        w[r] = m;
#pragma unroll
        for (int q = 0; q < 4; ++q) e[q] = (e[q] == m) ? 0xFFFFFFFFu : e[q];
    }

    // sort winners by column index: rotate to (col12 << 20 | score16 << 4), Batcher-8
    u32 s[8];
#pragma unroll
    for (int r = 0; r < KRET; ++r) s[r] = (w[r] << 20) | (w[r] >> 12);
    s[7] = 0xFFFFFFFFu;
#define CE(x, y) { u32 lo = minu32(s[x], s[y]); u32 hi2 = maxu32(s[x], s[y]); s[x] = lo; s[y] = hi2; }
    CE(0,1) CE(2,3) CE(4,5) CE(6,7)
    CE(0,2) CE(1,3) CE(4,6) CE(5,7)
    CE(1,2) CE(5,6)
    CE(0,4) CE(1,5) CE(2,6) CE(3,7)
    CE(2,4) CE(3,5)
    CE(1,2) CE(3,4) CE(5,6)
#undef CE

    const int ig = i & (SPC - 1);
    float ls = 0.f, cnt = 0.f;
    bool any = false;
    bool v[KRET];
    int nidx[KRET];
#pragma unroll
    for (int k = 0; k < KRET; ++k) {
        nidx[k] = (int)(s[k] >> 20);
        const float d2n = __uint_as_float(((s[k] >> 4) & 0xFFFF0u) << 12);  // score16 << 16
        const float dneg = sqrtf(d2n);
        const int m = k + (k >= ig ? 1 : 0);
        const float dp = sqrtf(posd[(size_t)i * SPC + m]);
        v[k] = dp < dneg + MARGIN;       // wave-uniform
        any = any || v[k];
    }

    if (any) {
        const float a0 = emb[(size_t)i * D + lane];
        const float a1 = emb[(size_t)i * D + 64 + lane];
#pragma unroll
        for (int k = 0; k < KRET; ++k) {
            if (v[k]) {
                const int m = k + (k >= ig ? 1 : 0);
                const int tp = (i & ~(SPC - 1)) + m;
                const int tn = nidx[k];
                float d0 = emb[(size_t)tp * D + lane] - a0;
                float d1 = emb[(size_t)tp * D + 64 + lane] - a1;
                float sp = d0 * d0 + d1 * d1;
                float g0 = emb[(size_t)tn * D + lane] - a0;
                float g1 = emb[(size_t)tn * D + 64 + lane] - a1;
                float sn = g0 * g0 + g1 * g1;
#pragma unroll
                for (int off = 1; off < 64; off <<= 1) {
                    sp += __shfl_xor(sp, off, 64);
                    sn += __shfl_xor(sn, off, 64);
                }
                ls += (sqrtf(sp + 1e-8f) + MARGIN) + fmaxf(MARGIN - sqrtf(sn + 1e-8f), 0.f);
                cnt += 1.f;
            }
        }
    }
    if (lane == 0) {           // always write: poison-safe, deterministic
        rowls[i] = ls;
        rowcnt[i] = cnt;
    }
}

// ---- deterministic single-block reduction over 4096 per-row partials ----
__global__ __launch_bounds__(256) void finalize_kernel(const float* __restrict__ rowls,
                                                       const float* __restrict__ rowcnt,
                                                       float* __restrict__ out) {
    const int t = threadIdx.x;
    __shared__ float sls[4], scnt[4];
    float ls = 0.f, cnt = 0.f;
#pragma unroll
    for (int q = 0; q < NROWS / 256; ++q) {
        ls += rowls[q * 256 + t];
        cnt += rowcnt[q * 256 + t];
    }
#pragma unroll
    for (int off = 1; off < 64; off <<= 1) {
        ls += __shfl_xor(ls, off, 64);
        cnt += __shfl_xor(cnt, off, 64);
    }
    if ((t & 63) == 0) { sls[t >> 6] = ls; scnt[t >> 6] = cnt; }
    __syncthreads();
    if (t == 0) {
        float L = sls[0] + sls[1] + sls[2] + sls[3];
        float C = scnt[0] + scnt[1] + scnt[2] + scnt[3];
        out[0] = C > 0.f ? L / C : L;
    }
}

// ---------------- Fallback path (round-1, only if ws too small) ----------------
__global__ __launch_bounds__(256) void diag_kernel(const float* __restrict__ emb,
                                                   const float* __restrict__ emb1,
                                                   float* __restrict__ diag) {
    int wave = threadIdx.x >> 6;
    int lane = threadIdx.x & 63;
    int row = blockIdx.x * 4 + wave;
    const float* a = emb + (size_t)row * D;
    const float* b = emb1 + (size_t)row * D;
    float s = a[lane] * b[lane] + a[lane + 64] * b[lane + 64];
    for (int off = 32; off > 0; off >>= 1) s += __shfl_down(s, off, 64);
    if (lane == 0) diag[row] = s;
}

__global__ __launch_bounds__(256) void main_kernel(const float* __restrict__ emb,
                                                   const float* __restrict__ emb1,
                                                   const int* __restrict__ labels,
                                                   const int* __restrict__ labels1,
                                                   const float* __restrict__ diag,
                                                   float* __restrict__ ws_acc) {
    const int i = blockIdx.x;
    const int tid = threadIdx.x;
    __shared__ float s_anchor[D];
    __shared__ float s_posd[SPC];
    __shared__ u64 s_red[4];
    __shared__ u64 s_win;
    __shared__ int s_negidx[KRET];
    __shared__ float s_negd[KRET];
    __shared__ float s_dreal[2 * KRET];

    if (tid < D) s_anchor[tid] = emb[(size_t)i * D + tid];
    __syncthreads();
    const float diag_i = diag[i];
    const int li = labels1[i];
    float score[16];
#pragma unroll
    for (int it = 0; it < 16; ++it) {
        int j = it * 256 + tid;
        const float4* r = (const float4*)(emb1 + (size_t)j * D);
        float acc = 0.f;
#pragma unroll
        for (int q = 0; q < D / 4; ++q) {
            float4 vv = r[q];
            acc = fmaf(vv.x, s_anchor[4 * q + 0], acc);
            acc = fmaf(vv.y, s_anchor[4 * q + 1], acc);
            acc = fmaf(vv.z, s_anchor[4 * q + 2], acc);
            acc = fmaf(vv.w, s_anchor[4 * q + 3], acc);
        }
        float d2 = diag_i + diag[j] - 2.f * acc;
        float dist = sqrtf(fmaxf(d2, 1e-4f));
        bool is_pos = (labels[j] == li) && (j != i);
        if (is_pos) s_posd[j & (SPC - 1)] = dist;
        score[it] = dist + (is_pos ? 1e6f : 0.f);
    }
    __syncthreads();
    for (int r = 0; r < KRET; ++r) {
        u64 best = ~0ull;
#pragma unroll
        for (int it = 0; it < 16; ++it) {
            u64 p = ((u64)__float_as_uint(score[it]) << 32) | (unsigned)(it * 256 + tid);
            best = best < p ? best : p;
        }
        for (int off = 32; off > 0; off >>= 1) {
            u64 o = __shfl_down(best, off, 64);
            best = best < o ? best : o;
        }
        if ((tid & 63) == 0) s_red[tid >> 6] = best;
        __syncthreads();
        if (tid == 0) {
            u64 w2 = s_red[0];
            w2 = w2 < s_red[1] ? w2 : s_red[1];
            w2 = w2 < s_red[2] ? w2 : s_red[2];
            w2 = w2 < s_red[3] ? w2 : s_red[3];
            s_win = w2;
        }
        __syncthreads();
        u64 w2 = s_win;
        int cj = (int)(w2 & 0xffffffffu);
        if (tid == (cj & 255)) score[cj >> 8] = 1e30f;
        if (tid == 0) { s_negidx[r] = cj; s_negd[r] = __uint_as_float((unsigned)(w2 >> 32)); }
        __syncthreads();
    }
    if (tid == 0) {
        for (int a = 1; a < KRET; ++a) {
            int ix = s_negidx[a]; float dv = s_negd[a];
            int b = a - 1;
            while (b >= 0 && s_negidx[b] > ix) {
                s_negidx[b + 1] = s_negidx[b]; s_negd[b + 1] = s_negd[b]; --b;
            }
            s_negidx[b + 1] = ix; s_negd[b + 1] = dv;
        }
    }
    __syncthreads();
    {
        int wave = tid >> 6, lane = tid & 63;
        int gb = i & ~(SPC - 1);
        for (int p = wave; p < 2 * KRET; p += 4) {
            int tgt;
            if (p < KRET) {
                int k = p;
                int m = k + (k >= (i & (SPC - 1)) ? 1 : 0);
                tgt = gb + m;
            } else tgt = s_negidx[p - KRET];
            float d0 = emb[(size_t)tgt * D + lane] - s_anchor[lane];
            float d1 = emb[(size_t)tgt * D + 64 + lane] - s_anchor[64 + lane];
            float s = d0 * d0 + d1 * d1;
            for (int off = 32; off > 0; off >>= 1) s += __shfl_down(s, off, 64);
            if (lane == 0) s_dreal[p] = sqrtf(s + 1e-8f);
        }
    }
    __syncthreads();
    if (tid == 0) {
        float ls = 0.f, cnt = 0.f;
        for (int k = 0; k < KRET; ++k) {
            int m = k + (k >= (i & (SPC - 1)) ? 1 : 0);
            if (s_posd[m] < s_negd[k] + MARGIN) {
                ls += (s_dreal[k] + MARGIN) + fmaxf(MARGIN - s_dreal[KRET + k], 0.f);
                cnt += 1.f;
            }
        }
        if (ls != 0.f) atomicAdd(&ws_acc[0], ls);
        if (cnt != 0.f) atomicAdd(&ws_acc[1], cnt);
    }
}

__global__ void finalize_ws(const float* __restrict__ ws_acc, float* __restrict__ out) {
    float ls = ws_acc[0], cnt = ws_acc[1];
    out[0] = cnt > 0.f ? ls / cnt : ls;
}

extern "C" void kernel_launch(void* const* d_in, const int* in_sizes, int n_in,
                              void* d_out, int out_size, void* d_ws, size_t ws_size,
                              hipStream_t stream) {
    const float* emb     = (const float*)d_in[0];
    const int*   labels  = (const int*)d_in[1];
    const float* emb1    = (const float*)d_in[2];
    const int*   labels1 = (const int*)d_in[3];
    float* ws = (float*)d_ws;

    const size_t need = (size_t)2015232 * sizeof(float);
    if (ws_size >= need) {
        float*  diag   = ws + 4096;
        float*  posd   = ws + 8192;
        ushort* embH   = (ushort*)(ws + 40960);
        ushort* emb1H  = (ushort*)(ws + 106496);
        u32*    cand   = (u32*)(ws + 172032);
        float*  rowls  = ws + 2007040;
        float*  rowcnt = ws + 2011136;

        prep_kernel<<<NROWS / 4, 256, 0, stream>>>(emb, emb1, embH, emb1H, diag);
        dim3 grid(NROWS / 128, NROWS / 128);
        dist_mfma<<<grid, 256, 0, stream>>>(embH, emb1H, labels, labels1, diag, posd, cand);
        merge_kernel<<<NROWS / 4, 256, 0, stream>>>(emb, posd, cand, rowls, rowcnt);
        finalize_kernel<<<1, 256, 0, stream>>>(rowls, rowcnt, (float*)d_out);
    } else {
        hipMemsetAsync(d_ws, 0, 2 * sizeof(float), stream);
        float* diag = ws + 2;
        diag_kernel<<<NROWS / 4, 256, 0, stream>>>(emb, emb1, diag);
        main_kernel<<<NROWS, 256, 0, stream>>>(emb, emb1, labels, labels1, diag, ws);
        finalize_ws<<<1, 1, 0, stream>>>(ws, (float*)d_out);
    }
}